// Round 2
// baseline (288.933 us; speedup 1.0000x reference)
//
#include <hip/hip_runtime.h>
#include <hip/hip_bf16.h>
#include <math.h>

// B=16, S=2048, D=1024, HD=64
constexpr int Bsz  = 16;
constexpr int Seq  = 2048;
constexpr int Din  = 1024;
constexpr int Hd   = 64;
constexpr int Rows = Bsz * Seq;   // 32768

typedef short  short8 __attribute__((ext_vector_type(8)));
typedef float  f32x4  __attribute__((ext_vector_type(4)));

__device__ __forceinline__ short bf16_bits(float f) {
    __hip_bfloat16 h = __float2bfloat16(f);   // RNE
    return __builtin_bit_cast(short, h);
}

// async global->LDS, 16B per lane (dest = lds base + lane*16)
typedef __attribute__((address_space(1))) const void gvoid_t;
typedef __attribute__((address_space(3))) void lvoid_t;
__device__ __forceinline__ void gll16(const void* g, void* l) {
    __builtin_amdgcn_global_load_lds((gvoid_t*)g, (lvoid_t*)l, 16, 0, 0);
}

// ---------------------------------------------------------------------------
// Wf fragment order: [chunk k/32][f = wg*4+nt][lane = quad*16+l16][j 0..8)
//   holds W_wg[k = chunk*32 + quad*8 + j][n = nt*16 + l16]
// ---------------------------------------------------------------------------
__global__ __launch_bounds__(256) void wt_prep(
    const float* __restrict__ Wq, const float* __restrict__ Wk,
    const float* __restrict__ Wv, short* __restrict__ Wf)
{
    const int u     = blockIdx.x * 256 + threadIdx.x;   // 0..24575
    const int chunk = u / 768;
    const int rem   = u - chunk * 768;
    const int f     = rem >> 6;
    const int lane  = rem & 63;
    const int wg    = f >> 2, nt = f & 3;
    const int quad  = lane >> 4, l16 = lane & 15;
    const float* W  = (wg == 0) ? Wq : (wg == 1) ? Wk : Wv;
    const int k0 = chunk * 32 + quad * 8;
    const int n  = nt * 16 + l16;
    short8 v;
    #pragma unroll
    for (int j = 0; j < 8; ++j) v[j] = bf16_bits(W[(size_t)(k0 + j) * Hd + n]);
    *(short8*)(Wf + (size_t)u * 8) = v;
}

// ---------------------------------------------------------------------------
// QKV v7: 32-row blocks, grid 1024 (4 blocks/CU, 4 waves/SIMD).
// Wave (g = w>>1, h = w&1): 16 rows (group g) x 6 fragments (half h).
//   h=0: frags 0-5  = Q nt0-3, K nt0-1
//   h=1: frags 6-11 = K nt2-3, V nt0-3
// LDS-staged Wf (global_load_lds, double-buffered) + x reg prefetch.
// ---------------------------------------------------------------------------
__global__ __launch_bounds__(256) void qkv_kernel(
    const float* __restrict__ x,
    const short* __restrict__ Wf,
    const float* __restrict__ bq, const float* __restrict__ bk,
    const float* __restrict__ bv,
    short* __restrict__ Qf, short* __restrict__ Kf, short* __restrict__ Vf)
{
    const int tid  = threadIdx.x;
    const int wave = tid >> 6;
    const int lane = tid & 63;
    const int quad = lane >> 4;
    const int l16  = lane & 15;
    const int g    = wave >> 1;     // row-group (16 rows each)
    const int h    = wave & 1;      // fragment half
    const int bx   = blockIdx.x;
    const int m0   = bx * 32;

    // 24576 B LDS: K-loop dbuf sW[2][6144] shorts; epilogue aliases it.
    __shared__ __align__(16) short smem[12288];
    short* sW = smem;

    const float* xrow = x + (size_t)(m0 + g * 16 + l16) * Din + quad * 8;

    f32x4 acc[6] = {};

    // ---- prologue: stage chunk 0, prefetch x chunk 0 ----
    {
        const short* gp = Wf + wave * 1536 + lane * 8;
        short*       lp = sW + wave * 1536;
        gll16(gp,        lp);
        gll16(gp +  512, lp +  512);
        gll16(gp + 1024, lp + 1024);
    }
    float4 a0 = *(const float4*)(xrow);
    float4 a1 = *(const float4*)(xrow + 4);
    __syncthreads();   // vmcnt(0) drain -> buf0 + x0 ready

    for (int c = 0; c < 32; ++c) {
        const int cur = (c & 1) * 6144;
        // stage next Wf chunk into the other buffer (async, drains at barrier)
        if (c < 31) {
            const short* gp = Wf + (size_t)(c + 1) * 6144 + wave * 1536 + lane * 8;
            short*       lp = sW + (cur ^ 6144) + wave * 1536;
            gll16(gp,        lp);
            gll16(gp +  512, lp +  512);
            gll16(gp + 1024, lp + 1024);
        }
        // prefetch next x slice into registers
        float4 b0 = a0, b1 = a1;
        if (c < 31) {
            b0 = *(const float4*)(xrow + (c + 1) * 32);
            b1 = *(const float4*)(xrow + (c + 1) * 32 + 4);
        }
        short8 af;
        af[0] = bf16_bits(a0.x); af[1] = bf16_bits(a0.y);
        af[2] = bf16_bits(a0.z); af[3] = bf16_bits(a0.w);
        af[4] = bf16_bits(a1.x); af[5] = bf16_bits(a1.y);
        af[6] = bf16_bits(a1.z); af[7] = bf16_bits(a1.w);
        const short* wsrc = sW + cur + h * 3072 + lane * 8;  // 16B/lane: conflict-free
        #pragma unroll
        for (int i = 0; i < 6; ++i) {
            const short8 bb = *(const short8*)(wsrc + i * 512);
            acc[i] = __builtin_amdgcn_mfma_f32_16x16x32_bf16(af, bb, acc[i], 0, 0, 0);
        }
        a0 = b0; a1 = b1;
        __syncthreads();   // all reads of buf done + next stage complete
    }

    // ---- epilogue (aliased LDS) ----
    // eS[g][0]=Q strip, eS[g][1]=K strip (16 rows x 72 stride); eV [64][44].
    short (*eS)[2][1152] = reinterpret_cast<short(*)[2][1152]>(smem);
    short* eV = smem + 4608;

    if (h == 0) {
        // Q: acc[0..3] -> private strip -> A-layout store (no barrier needed)
        #pragma unroll
        for (int nt = 0; nt < 4; ++nt) {
            const float bb = bq[nt * 16 + l16];
            #pragma unroll
            for (int r = 0; r < 4; ++r)
                eS[g][0][(quad * 4 + r) * 72 + nt * 16 + l16] =
                    bf16_bits(acc[nt][r] + bb);
        }
        // K nt0,1: acc[4],acc[5]
        #pragma unroll
        for (int nt = 0; nt < 2; ++nt) {
            const float bb = bk[nt * 16 + l16];
            #pragma unroll
            for (int r = 0; r < 4; ++r)
                eS[g][1][(quad * 4 + r) * 72 + nt * 16 + l16] =
                    bf16_bits(acc[4 + nt][r] + bb);
        }
        const short8 v0 = *(const short8*)&eS[g][0][l16 * 72 + quad * 8];
        const short8 v1 = *(const short8*)&eS[g][0][l16 * 72 + 32 + quad * 8];
        const size_t tg = (size_t)bx * 2 + g;
        *(short8*)(Qf + (tg * 2 + 0) * 512 + lane * 8) = v0;
        *(short8*)(Qf + (tg * 2 + 1) * 512 + lane * 8) = v1;
    } else {
        // K nt2,3: acc[0],acc[1]
        #pragma unroll
        for (int nt = 0; nt < 2; ++nt) {
            const float bb = bk[(2 + nt) * 16 + l16];
            #pragma unroll
            for (int r = 0; r < 4; ++r)
                eS[g][1][(quad * 4 + r) * 72 + (2 + nt) * 16 + l16] =
                    bf16_bits(acc[nt][r] + bb);
        }
        // V: acc[2..5] -> [d][token] transpose buffer
        #pragma unroll
        for (int nt = 0; nt < 4; ++nt) {
            const float bb = bv[nt * 16 + l16];
            #pragma unroll
            for (int r = 0; r < 4; ++r)
                eV[(nt * 16 + l16) * 44 + g * 16 + quad * 4 + r] =
                    bf16_bits(acc[2 + nt][r] + bb);
        }
    }
    __syncthreads();

    // K store: h=0 waves read the (now complete) K strip of their group
    if (h == 0) {
        const short8 v0 = *(const short8*)&eS[g][1][l16 * 72 + quad * 8];
        const short8 v1 = *(const short8*)&eS[g][1][l16 * 72 + 32 + quad * 8];
        const size_t t  = bx >> 1;
        const int    nt = (bx & 1) * 2 + g;
        *(short8*)(Kf + ((t * 2 + 0) * 4 + nt) * 512 + lane * 8) = v0;
        *(short8*)(Kf + ((t * 2 + 1) * 4 + nt) * 512 + lane * 8) = v1;
    }
    // V store: all 4 waves, ntd = wave; block covers token-half ks = bx&1
    {
        const size_t t  = bx >> 1;
        const int    ks = bx & 1;
        const short8 v  = *(const short8*)&eV[(wave * 16 + l16) * 44 + quad * 8];
        *(short8*)(Vf + ((t * 2 + ks) * 4 + wave) * 512 + lane * 8) = v;
    }
}

// ---------------------------------------------------------------------------
// Flash attention v5 + setprio: split-kt across 4 waves of one 16-row q strip
// + LDS merge.  grid (128, 16) x 256.  Loop is barrier-free (per-wave state).
// ---------------------------------------------------------------------------
__global__ __launch_bounds__(256) void attn_kernel(
    const short* __restrict__ Qf, const short* __restrict__ Kf,
    const short* __restrict__ Vf, float* __restrict__ out)
{
    const int tid  = threadIdx.x;
    const int wave = tid >> 6;
    const int lane = tid & 63;
    const int quad = lane >> 4;
    const int l16  = lane & 15;
    const int b    = blockIdx.y;
    const int bx   = blockIdx.x;
    const int qs   = (bx & 1) ? (127 - (bx >> 1)) : (bx >> 1);  // balance remap
    const int dTile = qs >> 2;
    const int tiles = dTile + 1;
    const int qoff  = (qs & 3) * 16;

    __shared__ __align__(16) unsigned char sm[17408 + 512];
    short* Ps   = (short*)sm;              // [4][16*72] per-wave strips (loop)
    float* Obuf = (float*)sm;              // [4][16][68]  (merge; aliases Ps)
    float* mb   = (float*)(sm + 17408);    // [4][16]
    float* lb   = mb + 64;                 // [4][16]

    // Q fragments, loaded once (coalesced)
    const size_t tg = (size_t)b * 128 + qs;
    const short8 qf0 = *(const short8*)(Qf + (tg * 2 + 0) * 512 + lane * 8);
    const short8 qf1 = *(const short8*)(Qf + (tg * 2 + 1) * 512 + lane * 8);

    f32x4 o[4] = {};
    float m_run[4], l_run[4];
    #pragma unroll
    for (int r = 0; r < 4; ++r) { m_run[r] = -INFINITY; l_run[r] = 0.0f; }

    const float C = 0.125f * 1.44269504088896340736f;  // scale * log2(e)

    for (int kt = wave; kt < tiles; kt += 4) {
        const short* ktile = Kf + (size_t)(b * 32 + kt) * 4096;
        const short* vtile = Vf + (size_t)(b * 32 + kt) * 4096;

        f32x4 s[4] = {};
        __builtin_amdgcn_s_setprio(1);
        #pragma unroll
        for (int nt = 0; nt < 4; ++nt) {
            const short8 kf0 = *(const short8*)(ktile + ((0 * 4 + nt) * 64 + lane) * 8);
            const short8 kf1 = *(const short8*)(ktile + ((1 * 4 + nt) * 64 + lane) * 8);
            s[nt] = __builtin_amdgcn_mfma_f32_16x16x32_bf16(qf0, kf0, s[nt], 0, 0, 0);
            s[nt] = __builtin_amdgcn_mfma_f32_16x16x32_bf16(qf1, kf1, s[nt], 0, 0, 0);
        }
        __builtin_amdgcn_s_setprio(0);

        if (kt == dTile) {
            #pragma unroll
            for (int nt = 0; nt < 4; ++nt) {
                const int kg = nt * 16 + l16;
                #pragma unroll
                for (int r = 0; r < 4; ++r) {
                    const int qg = qoff + quad * 4 + r;
                    s[nt][r] = (kg <= qg) ? s[nt][r] * C : -INFINITY;
                }
            }
        } else {
            #pragma unroll
            for (int nt = 0; nt < 4; ++nt)
                #pragma unroll
                for (int r = 0; r < 4; ++r) s[nt][r] *= C;
        }

        float rm[4];
        #pragma unroll
        for (int r = 0; r < 4; ++r)
            rm[r] = fmaxf(fmaxf(s[0][r], s[1][r]), fmaxf(s[2][r], s[3][r]));
        #pragma unroll
        for (int off = 1; off < 16; off <<= 1)
            #pragma unroll
            for (int r = 0; r < 4; ++r)
                rm[r] = fmaxf(rm[r], __shfl_xor(rm[r], off));

        float alpha[4];
        #pragma unroll
        for (int r = 0; r < 4; ++r) {
            const float mn = fmaxf(m_run[r], rm[r]);
            alpha[r] = exp2f(m_run[r] - mn);
            m_run[r] = mn;
        }

        float rs[4] = {0.f, 0.f, 0.f, 0.f};
        #pragma unroll
        for (int nt = 0; nt < 4; ++nt)
            #pragma unroll
            for (int r = 0; r < 4; ++r) {
                const float p = exp2f(s[nt][r] - m_run[r]);
                s[nt][r] = p;
                rs[r] += p;
            }
        #pragma unroll
        for (int off = 1; off < 16; off <<= 1)
            #pragma unroll
            for (int r = 0; r < 4; ++r)
                rs[r] += __shfl_xor(rs[r], off);
        #pragma unroll
        for (int r = 0; r < 4; ++r) l_run[r] = l_run[r] * alpha[r] + rs[r];

        #pragma unroll
        for (int r = 0; r < 4; ++r) {
            o[0][r] *= alpha[r]; o[1][r] *= alpha[r];
            o[2][r] *= alpha[r]; o[3][r] *= alpha[r];
        }

        // P: C-layout -> A-layout via per-wave-private strip (stride 72!)
        #pragma unroll
        for (int nt = 0; nt < 4; ++nt)
            #pragma unroll
            for (int r = 0; r < 4; ++r)
                Ps[wave * 1152 + (quad * 4 + r) * 72 + nt * 16 + l16] = bf16_bits(s[nt][r]);

        const short8 pf0 = *(const short8*)&Ps[wave * 1152 + l16 * 72 + quad * 8];
        const short8 pf1 = *(const short8*)&Ps[wave * 1152 + l16 * 72 + 32 + quad * 8];

        __builtin_amdgcn_s_setprio(1);
        #pragma unroll
        for (int nt = 0; nt < 4; ++nt) {
            const short8 vA = *(const short8*)(vtile + ((0 * 4 + nt) * 64 + lane) * 8);
            const short8 vB = *(const short8*)(vtile + ((1 * 4 + nt) * 64 + lane) * 8);
            o[nt] = __builtin_amdgcn_mfma_f32_16x16x32_bf16(pf0, vA, o[nt], 0, 0, 0);
            o[nt] = __builtin_amdgcn_mfma_f32_16x16x32_bf16(pf1, vB, o[nt], 0, 0, 0);
        }
        __builtin_amdgcn_s_setprio(0);
    }

    // ---- 4-wave merge ----
    if (l16 == 0) {
        #pragma unroll
        for (int r = 0; r < 4; ++r) mb[wave * 16 + quad * 4 + r] = m_run[r];
    }
    __syncthreads();   // all waves done with loop (Ps free); mb ready

    float fac[4];
    #pragma unroll
    for (int r = 0; r < 4; ++r) {
        const int row = quad * 4 + r;
        const float mg = fmaxf(fmaxf(mb[row], mb[16 + row]),
                               fmaxf(mb[32 + row], mb[48 + row]));
        fac[r] = exp2f(m_run[r] - mg);   // -inf -> 0 for idle waves
    }
    if (l16 == 0) {
        #pragma unroll
        for (int r = 0; r < 4; ++r) lb[wave * 16 + quad * 4 + r] = l_run[r] * fac[r];
    }
    #pragma unroll
    for (int nt = 0; nt < 4; ++nt)
        #pragma unroll
        for (int r = 0; r < 4; ++r)
            Obuf[wave * 1088 + (quad * 4 + r) * 68 + nt * 16 + l16] = o[nt][r] * fac[r];
    __syncthreads();

    // reduce 4 partials + store (coalesced float4)
    {
        const int row = tid >> 4;
        const int c0  = (tid & 15) * 4;
        const float lsum = lb[row] + lb[16 + row] + lb[32 + row] + lb[48 + row];
        float4 a = *(const float4*)&Obuf[0 * 1088 + row * 68 + c0];
        const float4 a1 = *(const float4*)&Obuf[1 * 1088 + row * 68 + c0];
        const float4 a2 = *(const float4*)&Obuf[2 * 1088 + row * 68 + c0];
        const float4 a3 = *(const float4*)&Obuf[3 * 1088 + row * 68 + c0];
        a.x += a1.x + a2.x + a3.x;  a.y += a1.y + a2.y + a3.y;
        a.z += a1.z + a2.z + a3.z;  a.w += a1.w + a2.w + a3.w;
        const float inv = 1.0f / lsum;
        float4 r4 = make_float4(a.x * inv, a.y * inv, a.z * inv, a.w * inv);
        *(float4*)(out + ((size_t)b * Seq + qs * 16 + row) * Hd + c0) = r4;
    }
}

// ---------------------------------------------------------------------------
extern "C" void kernel_launch(void* const* d_in, const int* in_sizes, int n_in,
                              void* d_out, int out_size, void* d_ws, size_t ws_size,
                              hipStream_t stream)
{
    const float* x  = (const float*)d_in[0];
    const float* Wq = (const float*)d_in[1];
    const float* bq = (const float*)d_in[2];
    const float* Wk = (const float*)d_in[3];
    const float* bk = (const float*)d_in[4];
    const float* Wv = (const float*)d_in[5];
    const float* bv = (const float*)d_in[6];
    float* out = (float*)d_out;

    short* Qf = (short*)d_ws;                    // 4 MB
    short* Kf = Qf + (size_t)Rows * Hd;          // 4 MB
    short* Vf = Kf + (size_t)Rows * Hd;          // 4 MB
    short* Wf = Vf + (size_t)Rows * Hd;          // 384 KB

    wt_prep<<<96, 256, 0, stream>>>(Wq, Wk, Wv, Wf);
    qkv_kernel<<<1024, 256, 0, stream>>>(x, Wf, bq, bk, bv, Qf, Kf, Vf);
    attn_kernel<<<dim3(128, 16), 256, 0, stream>>>(Qf, Kf, Vf, out);
}

// Round 3
// 282.491 us; speedup vs baseline: 1.0228x; 1.0228x over previous
//
#include <hip/hip_runtime.h>
#include <hip/hip_bf16.h>
#include <math.h>

// B=16, S=2048, D=1024, HD=64
constexpr int Bsz  = 16;
constexpr int Seq  = 2048;
constexpr int Din  = 1024;
constexpr int Hd   = 64;
constexpr int Rows = Bsz * Seq;   // 32768

typedef short  short8 __attribute__((ext_vector_type(8)));
typedef float  f32x4  __attribute__((ext_vector_type(4)));

__device__ __forceinline__ short bf16_bits(float f) {
    __hip_bfloat16 h = __float2bfloat16(f);   // RNE
    return __builtin_bit_cast(short, h);
}

// async global->LDS, 16B per lane (dest = lds base + lane*16)
typedef __attribute__((address_space(1))) const void gvoid_t;
typedef __attribute__((address_space(3))) void lvoid_t;
__device__ __forceinline__ void gll16(const void* g, void* l) {
    __builtin_amdgcn_global_load_lds((gvoid_t*)g, (lvoid_t*)l, 16, 0, 0);
}

// ---------------------------------------------------------------------------
// Wf fragment order: [chunk k/32][f = wg*4+nt][lane = quad*16+l16][j 0..8)
//   holds W_wg[k = chunk*32 + quad*8 + j][n = nt*16 + l16]
// ---------------------------------------------------------------------------
__global__ __launch_bounds__(256) void wt_prep(
    const float* __restrict__ Wq, const float* __restrict__ Wk,
    const float* __restrict__ Wv, short* __restrict__ Wf)
{
    const int u     = blockIdx.x * 256 + threadIdx.x;   // 0..24575
    const int chunk = u / 768;
    const int rem   = u - chunk * 768;
    const int f     = rem >> 6;
    const int lane  = rem & 63;
    const int wg    = f >> 2, nt = f & 3;
    const int quad  = lane >> 4, l16 = lane & 15;
    const float* W  = (wg == 0) ? Wq : (wg == 1) ? Wk : Wv;
    const int k0 = chunk * 32 + quad * 8;
    const int n  = nt * 16 + l16;
    short8 v;
    #pragma unroll
    for (int j = 0; j < 8; ++j) v[j] = bf16_bits(W[(size_t)(k0 + j) * Hd + n]);
    *(short8*)(Wf + (size_t)u * 8) = v;
}

// ---------------------------------------------------------------------------
// QKV v8: counted-vmcnt pipeline (no vmcnt(0) drain in the K-loop).
// 32-row blocks, grid 1024 (4 blocks/CU).  Wave (g,h): 16 rows x 6 frags.
// Triple-buffered Wf staging (stage 2 ahead), x reg-prefetch depth 2.
// Per iter end: s_waitcnt vmcnt(7) lgkmcnt(0); s_barrier  -- leaves the
// newest {x(c+1):2, st(c+2):3, x(c+2):2} = 7 loads in flight across the
// barrier while guaranteeing st(c+1) (next iter's buffer) has landed.
// ---------------------------------------------------------------------------
__global__ __launch_bounds__(256) void qkv_kernel(
    const float* __restrict__ x,
    const short* __restrict__ Wf,
    const float* __restrict__ bq, const float* __restrict__ bk,
    const float* __restrict__ bv,
    short* __restrict__ Qf, short* __restrict__ Kf, short* __restrict__ Vf)
{
    const int tid  = threadIdx.x;
    const int wave = tid >> 6;
    const int lane = tid & 63;
    const int quad = lane >> 4;
    const int l16  = lane & 15;
    const int g    = wave >> 1;     // row-group (16 rows each)
    const int h    = wave & 1;      // fragment half
    const int bx   = blockIdx.x;
    const int m0   = bx * 32;

    // 36864 B LDS: K-loop triple buffer sW[3][6144] shorts; epilogue aliases
    // only the first 7424 shorts (buf0 + part of buf1).
    __shared__ __align__(16) short smem[18432];
    short* sW = smem;

    const float* xrow = x + (size_t)(m0 + g * 16 + l16) * Din + quad * 8;

    f32x4 acc[6] = {};

    // ---- prologue: stage chunks 0,1 -> buf0,buf1; x(0),x(1) -> regs ----
    {
        const short* gp = Wf + wave * 1536 + lane * 8;
        short*       lp = sW + wave * 1536;
        gll16(gp,        lp);
        gll16(gp +  512, lp +  512);
        gll16(gp + 1024, lp + 1024);
        const short* gp1 = gp + 6144;
        short*       lp1 = lp + 6144;
        gll16(gp1,        lp1);
        gll16(gp1 +  512, lp1 +  512);
        gll16(gp1 + 1024, lp1 + 1024);
    }
    asm volatile("" ::: "memory");   // pin: stages issued before x loads
    float4 a0 = *(const float4*)(xrow);
    float4 a1 = *(const float4*)(xrow + 4);
    float4 b0 = *(const float4*)(xrow + 32);
    float4 b1 = *(const float4*)(xrow + 36);
    // need st(0) done; newer ops = st(1):3 + x(0):2 + x(1):2 = 7
    asm volatile("s_waitcnt vmcnt(7)" ::: "memory");
    __builtin_amdgcn_s_barrier();

    int rd = 0;      // buffer holding chunk c
    int st = 2;      // buffer to stage chunk c+2 into
    for (int c = 0; c < 32; ++c) {
        // stage chunk c+2 (async; stays in flight across this iter's barrier)
        if (c + 2 < 32) {
            const short* gp = Wf + (size_t)(c + 2) * 6144 + wave * 1536 + lane * 8;
            short*       lp = sW + st * 6144 + wave * 1536;
            gll16(gp,        lp);
            gll16(gp +  512, lp +  512);
            gll16(gp + 1024, lp + 1024);
        }
        asm volatile("" ::: "memory");   // pin: stages before x loads
        // prefetch x slice c+2
        float4 n0 = b0, n1 = b1;
        if (c + 2 < 32) {
            n0 = *(const float4*)(xrow + (c + 2) * 32);
            n1 = *(const float4*)(xrow + (c + 2) * 32 + 4);
        }
        short8 af;
        af[0] = bf16_bits(a0.x); af[1] = bf16_bits(a0.y);
        af[2] = bf16_bits(a0.z); af[3] = bf16_bits(a0.w);
        af[4] = bf16_bits(a1.x); af[5] = bf16_bits(a1.y);
        af[6] = bf16_bits(a1.z); af[7] = bf16_bits(a1.w);
        const short* wsrc = sW + rd * 6144 + h * 3072 + lane * 8;  // 16B/lane
        #pragma unroll
        for (int i = 0; i < 6; ++i) {
            const short8 bb = *(const short8*)(wsrc + i * 512);
            acc[i] = __builtin_amdgcn_mfma_f32_16x16x32_bf16(af, bb, acc[i], 0, 0, 0);
        }
        a0 = b0; a1 = b1; b0 = n0; b1 = n1;
        rd = (rd == 2) ? 0 : rd + 1;
        st = (st == 2) ? 0 : st + 1;
        // publish buf(c+1): counted wait, never drain.  lgkmcnt(0) closes the
        // WAR race (my ds_reads complete before anyone's next-stage lands).
        if (c < 30) {
            asm volatile("s_waitcnt vmcnt(7) lgkmcnt(0)" ::: "memory");
            __builtin_amdgcn_s_barrier();
        } else if (c == 30) {
            asm volatile("s_waitcnt vmcnt(2) lgkmcnt(0)" ::: "memory");
            __builtin_amdgcn_s_barrier();
        }
        // c == 31: no barrier; iter 31 read buf2, epilogue uses buf0/1 region.
    }

    // ---- epilogue (aliased LDS) ----
    // eS[g][0]=Q strip, eS[g][1]=K strip (16 rows x 72 stride); eV [64][44].
    short (*eS)[2][1152] = reinterpret_cast<short(*)[2][1152]>(smem);
    short* eV = smem + 4608;

    if (h == 0) {
        // Q: acc[0..3] -> private strip -> A-layout store (no barrier needed)
        #pragma unroll
        for (int nt = 0; nt < 4; ++nt) {
            const float bb = bq[nt * 16 + l16];
            #pragma unroll
            for (int r = 0; r < 4; ++r)
                eS[g][0][(quad * 4 + r) * 72 + nt * 16 + l16] =
                    bf16_bits(acc[nt][r] + bb);
        }
        // K nt0,1: acc[4],acc[5]
        #pragma unroll
        for (int nt = 0; nt < 2; ++nt) {
            const float bb = bk[nt * 16 + l16];
            #pragma unroll
            for (int r = 0; r < 4; ++r)
                eS[g][1][(quad * 4 + r) * 72 + nt * 16 + l16] =
                    bf16_bits(acc[4 + nt][r] + bb);
        }
        const short8 v0 = *(const short8*)&eS[g][0][l16 * 72 + quad * 8];
        const short8 v1 = *(const short8*)&eS[g][0][l16 * 72 + 32 + quad * 8];
        const size_t tg = (size_t)bx * 2 + g;
        *(short8*)(Qf + (tg * 2 + 0) * 512 + lane * 8) = v0;
        *(short8*)(Qf + (tg * 2 + 1) * 512 + lane * 8) = v1;
    } else {
        // K nt2,3: acc[0],acc[1]
        #pragma unroll
        for (int nt = 0; nt < 2; ++nt) {
            const float bb = bk[(2 + nt) * 16 + l16];
            #pragma unroll
            for (int r = 0; r < 4; ++r)
                eS[g][1][(quad * 4 + r) * 72 + (2 + nt) * 16 + l16] =
                    bf16_bits(acc[nt][r] + bb);
        }
        // V: acc[2..5] -> [d][token] transpose buffer
        #pragma unroll
        for (int nt = 0; nt < 4; ++nt) {
            const float bb = bv[nt * 16 + l16];
            #pragma unroll
            for (int r = 0; r < 4; ++r)
                eV[(nt * 16 + l16) * 44 + g * 16 + quad * 4 + r] =
                    bf16_bits(acc[2 + nt][r] + bb);
        }
    }
    __syncthreads();

    // K store: h=0 waves read the (now complete) K strip of their group
    if (h == 0) {
        const short8 v0 = *(const short8*)&eS[g][1][l16 * 72 + quad * 8];
        const short8 v1 = *(const short8*)&eS[g][1][l16 * 72 + 32 + quad * 8];
        const size_t t  = bx >> 1;
        const int    nt = (bx & 1) * 2 + g;
        *(short8*)(Kf + ((t * 2 + 0) * 4 + nt) * 512 + lane * 8) = v0;
        *(short8*)(Kf + ((t * 2 + 1) * 4 + nt) * 512 + lane * 8) = v1;
    }
    // V store: all 4 waves, ntd = wave; block covers token-half ks = bx&1
    {
        const size_t t  = bx >> 1;
        const int    ks = bx & 1;
        const short8 v  = *(const short8*)&eV[(wave * 16 + l16) * 44 + quad * 8];
        *(short8*)(Vf + ((t * 2 + ks) * 4 + wave) * 512 + lane * 8) = v;
    }
}

// ---------------------------------------------------------------------------
// Flash attention v5 + setprio: split-kt across 4 waves of one 16-row q strip
// + LDS merge.  grid (128, 16) x 256.  Loop is barrier-free (per-wave state).
// ---------------------------------------------------------------------------
__global__ __launch_bounds__(256) void attn_kernel(
    const short* __restrict__ Qf, const short* __restrict__ Kf,
    const short* __restrict__ Vf, float* __restrict__ out)
{
    const int tid  = threadIdx.x;
    const int wave = tid >> 6;
    const int lane = tid & 63;
    const int quad = lane >> 4;
    const int l16  = lane & 15;
    const int b    = blockIdx.y;
    const int bx   = blockIdx.x;
    const int qs   = (bx & 1) ? (127 - (bx >> 1)) : (bx >> 1);  // balance remap
    const int dTile = qs >> 2;
    const int tiles = dTile + 1;
    const int qoff  = (qs & 3) * 16;

    __shared__ __align__(16) unsigned char sm[17408 + 512];
    short* Ps   = (short*)sm;              // [4][16*72] per-wave strips (loop)
    float* Obuf = (float*)sm;              // [4][16][68]  (merge; aliases Ps)
    float* mb   = (float*)(sm + 17408);    // [4][16]
    float* lb   = mb + 64;                 // [4][16]

    // Q fragments, loaded once (coalesced)
    const size_t tg = (size_t)b * 128 + qs;
    const short8 qf0 = *(const short8*)(Qf + (tg * 2 + 0) * 512 + lane * 8);
    const short8 qf1 = *(const short8*)(Qf + (tg * 2 + 1) * 512 + lane * 8);

    f32x4 o[4] = {};
    float m_run[4], l_run[4];
    #pragma unroll
    for (int r = 0; r < 4; ++r) { m_run[r] = -INFINITY; l_run[r] = 0.0f; }

    const float C = 0.125f * 1.44269504088896340736f;  // scale * log2(e)

    for (int kt = wave; kt < tiles; kt += 4) {
        const short* ktile = Kf + (size_t)(b * 32 + kt) * 4096;
        const short* vtile = Vf + (size_t)(b * 32 + kt) * 4096;

        f32x4 s[4] = {};
        __builtin_amdgcn_s_setprio(1);
        #pragma unroll
        for (int nt = 0; nt < 4; ++nt) {
            const short8 kf0 = *(const short8*)(ktile + ((0 * 4 + nt) * 64 + lane) * 8);
            const short8 kf1 = *(const short8*)(ktile + ((1 * 4 + nt) * 64 + lane) * 8);
            s[nt] = __builtin_amdgcn_mfma_f32_16x16x32_bf16(qf0, kf0, s[nt], 0, 0, 0);
            s[nt] = __builtin_amdgcn_mfma_f32_16x16x32_bf16(qf1, kf1, s[nt], 0, 0, 0);
        }
        __builtin_amdgcn_s_setprio(0);

        if (kt == dTile) {
            #pragma unroll
            for (int nt = 0; nt < 4; ++nt) {
                const int kg = nt * 16 + l16;
                #pragma unroll
                for (int r = 0; r < 4; ++r) {
                    const int qg = qoff + quad * 4 + r;
                    s[nt][r] = (kg <= qg) ? s[nt][r] * C : -INFINITY;
                }
            }
        } else {
            #pragma unroll
            for (int nt = 0; nt < 4; ++nt)
                #pragma unroll
                for (int r = 0; r < 4; ++r) s[nt][r] *= C;
        }

        float rm[4];
        #pragma unroll
        for (int r = 0; r < 4; ++r)
            rm[r] = fmaxf(fmaxf(s[0][r], s[1][r]), fmaxf(s[2][r], s[3][r]));
        #pragma unroll
        for (int off = 1; off < 16; off <<= 1)
            #pragma unroll
            for (int r = 0; r < 4; ++r)
                rm[r] = fmaxf(rm[r], __shfl_xor(rm[r], off));

        float alpha[4];
        #pragma unroll
        for (int r = 0; r < 4; ++r) {
            const float mn = fmaxf(m_run[r], rm[r]);
            alpha[r] = exp2f(m_run[r] - mn);
            m_run[r] = mn;
        }

        float rs[4] = {0.f, 0.f, 0.f, 0.f};
        #pragma unroll
        for (int nt = 0; nt < 4; ++nt)
            #pragma unroll
            for (int r = 0; r < 4; ++r) {
                const float p = exp2f(s[nt][r] - m_run[r]);
                s[nt][r] = p;
                rs[r] += p;
            }
        #pragma unroll
        for (int off = 1; off < 16; off <<= 1)
            #pragma unroll
            for (int r = 0; r < 4; ++r)
                rs[r] += __shfl_xor(rs[r], off);
        #pragma unroll
        for (int r = 0; r < 4; ++r) l_run[r] = l_run[r] * alpha[r] + rs[r];

        #pragma unroll
        for (int r = 0; r < 4; ++r) {
            o[0][r] *= alpha[r]; o[1][r] *= alpha[r];
            o[2][r] *= alpha[r]; o[3][r] *= alpha[r];
        }

        // P: C-layout -> A-layout via per-wave-private strip (stride 72!)
        #pragma unroll
        for (int nt = 0; nt < 4; ++nt)
            #pragma unroll
            for (int r = 0; r < 4; ++r)
                Ps[wave * 1152 + (quad * 4 + r) * 72 + nt * 16 + l16] = bf16_bits(s[nt][r]);

        const short8 pf0 = *(const short8*)&Ps[wave * 1152 + l16 * 72 + quad * 8];
        const short8 pf1 = *(const short8*)&Ps[wave * 1152 + l16 * 72 + 32 + quad * 8];

        __builtin_amdgcn_s_setprio(1);
        #pragma unroll
        for (int nt = 0; nt < 4; ++nt) {
            const short8 vA = *(const short8*)(vtile + ((0 * 4 + nt) * 64 + lane) * 8);
            const short8 vB = *(const short8*)(vtile + ((1 * 4 + nt) * 64 + lane) * 8);
            o[nt] = __builtin_amdgcn_mfma_f32_16x16x32_bf16(pf0, vA, o[nt], 0, 0, 0);
            o[nt] = __builtin_amdgcn_mfma_f32_16x16x32_bf16(pf1, vB, o[nt], 0, 0, 0);
        }
        __builtin_amdgcn_s_setprio(0);
    }

    // ---- 4-wave merge ----
    if (l16 == 0) {
        #pragma unroll
        for (int r = 0; r < 4; ++r) mb[wave * 16 + quad * 4 + r] = m_run[r];
    }
    __syncthreads();   // all waves done with loop (Ps free); mb ready

    float fac[4];
    #pragma unroll
    for (int r = 0; r < 4; ++r) {
        const int row = quad * 4 + r;
        const float mg = fmaxf(fmaxf(mb[row], mb[16 + row]),
                               fmaxf(mb[32 + row], mb[48 + row]));
        fac[r] = exp2f(m_run[r] - mg);   // -inf -> 0 for idle waves
    }
    if (l16 == 0) {
        #pragma unroll
        for (int r = 0; r < 4; ++r) lb[wave * 16 + quad * 4 + r] = l_run[r] * fac[r];
    }
    #pragma unroll
    for (int nt = 0; nt < 4; ++nt)
        #pragma unroll
        for (int r = 0; r < 4; ++r)
            Obuf[wave * 1088 + (quad * 4 + r) * 68 + nt * 16 + l16] = o[nt][r] * fac[r];
    __syncthreads();

    // reduce 4 partials + store (coalesced float4)
    {
        const int row = tid >> 4;
        const int c0  = (tid & 15) * 4;
        const float lsum = lb[row] + lb[16 + row] + lb[32 + row] + lb[48 + row];
        float4 a = *(const float4*)&Obuf[0 * 1088 + row * 68 + c0];
        const float4 a1 = *(const float4*)&Obuf[1 * 1088 + row * 68 + c0];
        const float4 a2 = *(const float4*)&Obuf[2 * 1088 + row * 68 + c0];
        const float4 a3 = *(const float4*)&Obuf[3 * 1088 + row * 68 + c0];
        a.x += a1.x + a2.x + a3.x;  a.y += a1.y + a2.y + a3.y;
        a.z += a1.z + a2.z + a3.z;  a.w += a1.w + a2.w + a3.w;
        const float inv = 1.0f / lsum;
        float4 r4 = make_float4(a.x * inv, a.y * inv, a.z * inv, a.w * inv);
        *(float4*)(out + ((size_t)b * Seq + qs * 16 + row) * Hd + c0) = r4;
    }
}

// ---------------------------------------------------------------------------
extern "C" void kernel_launch(void* const* d_in, const int* in_sizes, int n_in,
                              void* d_out, int out_size, void* d_ws, size_t ws_size,
                              hipStream_t stream)
{
    const float* x  = (const float*)d_in[0];
    const float* Wq = (const float*)d_in[1];
    const float* bq = (const float*)d_in[2];
    const float* Wk = (const float*)d_in[3];
    const float* bk = (const float*)d_in[4];
    const float* Wv = (const float*)d_in[5];
    const float* bv = (const float*)d_in[6];
    float* out = (float*)d_out;

    short* Qf = (short*)d_ws;                    // 4 MB
    short* Kf = Qf + (size_t)Rows * Hd;          // 4 MB
    short* Vf = Kf + (size_t)Rows * Hd;          // 4 MB
    short* Wf = Vf + (size_t)Rows * Hd;          // 384 KB

    wt_prep<<<96, 256, 0, stream>>>(Wq, Wk, Wv, Wf);
    qkv_kernel<<<1024, 256, 0, stream>>>(x, Wf, bq, bk, bv, Qf, Kf, Vf);
    attn_kernel<<<dim3(128, 16), 256, 0, stream>>>(Qf, Kf, Vf, out);
}

// Round 4
// 280.775 us; speedup vs baseline: 1.0291x; 1.0061x over previous
//
#include <hip/hip_runtime.h>
#include <hip/hip_bf16.h>
#include <math.h>

// B=16, S=2048, D=1024, HD=64
constexpr int Bsz  = 16;
constexpr int Seq  = 2048;
constexpr int Din  = 1024;
constexpr int Hd   = 64;
constexpr int Rows = Bsz * Seq;   // 32768

typedef short  short8 __attribute__((ext_vector_type(8)));
typedef float  f32x4  __attribute__((ext_vector_type(4)));

__device__ __forceinline__ short bf16_bits(float f) {
    __hip_bfloat16 h = __float2bfloat16(f);   // RNE
    return __builtin_bit_cast(short, h);
}

// async global->LDS, 16B per lane (dest = lds base + lane*16)
typedef __attribute__((address_space(1))) const void gvoid_t;
typedef __attribute__((address_space(3))) void lvoid_t;
__device__ __forceinline__ void gll16(const void* g, void* l) {
    __builtin_amdgcn_global_load_lds((gvoid_t*)g, (lvoid_t*)l, 16, 0, 0);
}

// ---------------------------------------------------------------------------
// Wf fragment order: [chunk k/32][f = wg*4+nt][lane = quad*16+l16][j 0..8)
//   holds W_wg[k = chunk*32 + quad*8 + j][n = nt*16 + l16]
// ---------------------------------------------------------------------------
__global__ __launch_bounds__(256) void wt_prep(
    const float* __restrict__ Wq, const float* __restrict__ Wk,
    const float* __restrict__ Wv, short* __restrict__ Wf)
{
    const int u     = blockIdx.x * 256 + threadIdx.x;   // 0..24575
    const int chunk = u / 768;
    const int rem   = u - chunk * 768;
    const int f     = rem >> 6;
    const int lane  = rem & 63;
    const int wg    = f >> 2, nt = f & 3;
    const int quad  = lane >> 4, l16 = lane & 15;
    const float* W  = (wg == 0) ? Wq : (wg == 1) ? Wk : Wv;
    const int k0 = chunk * 32 + quad * 8;
    const int n  = nt * 16 + l16;
    short8 v;
    #pragma unroll
    for (int j = 0; j < 8; ++j) v[j] = bf16_bits(W[(size_t)(k0 + j) * Hd + n]);
    *(short8*)(Wf + (size_t)u * 8) = v;
}

// ---------------------------------------------------------------------------
// QKV v9: v6 work shape (64-row blocks, grid 512, wave = 16 rows x ALL 12
// fragments -> 12 MFMA + 12 ds_read_b128 per iter = high per-wave ILP)
// + v8 wait discipline (triple-buffered Wf staging, stage 2 ahead, x reg
// prefetch depth 2, counted vmcnt: never drain in the K-loop).
// Per iter end: s_waitcnt vmcnt(7) lgkmcnt(0); s_barrier -- the 7 newest
// in-flight ops are {x(c+1):2, st(c+2):3, x(c+2):2}; the wait publishes
// buf(c+1) while keeping a 2-iteration latency window on x.
// ---------------------------------------------------------------------------
__global__ __launch_bounds__(256) void qkv_kernel(
    const float* __restrict__ x,
    const short* __restrict__ Wf,
    const float* __restrict__ bq, const float* __restrict__ bk,
    const float* __restrict__ bv,
    short* __restrict__ Qf, short* __restrict__ Kf, short* __restrict__ Vf)
{
    const int tid  = threadIdx.x;
    const int wave = tid >> 6;
    const int lane = tid & 63;
    const int quad = lane >> 4;
    const int l16  = lane & 15;
    const int bx   = blockIdx.x;
    const int m0   = bx * 64;

    // 36864 B LDS: K-loop triple buffer sW[3][6144] shorts.
    // Epilogue aliases smem[0..14336) -- protected by the post-loop barrier.
    __shared__ __align__(16) short smem[18432];
    short* sW = smem;

    const float* xrow = x + (size_t)(m0 + wave * 16 + l16) * Din + quad * 8;

    f32x4 acc[12] = {};

    // ---- prologue: stage chunks 0,1 -> buf0,buf1; x(0),x(1) -> regs ----
    {
        const short* gp = Wf + wave * 1536 + lane * 8;
        short*       lp = sW + wave * 1536;
        gll16(gp,        lp);
        gll16(gp +  512, lp +  512);
        gll16(gp + 1024, lp + 1024);
        const short* gp1 = gp + 6144;
        short*       lp1 = lp + 6144;
        gll16(gp1,        lp1);
        gll16(gp1 +  512, lp1 +  512);
        gll16(gp1 + 1024, lp1 + 1024);
    }
    asm volatile("" ::: "memory");   // pin: stages issued before x loads
    float4 a0 = *(const float4*)(xrow);
    float4 a1 = *(const float4*)(xrow + 4);
    float4 b0 = *(const float4*)(xrow + 32);
    float4 b1 = *(const float4*)(xrow + 36);
    // need st(0) done; newer ops = st(1):3 + x(0):2 + x(1):2 = 7
    asm volatile("s_waitcnt vmcnt(7)" ::: "memory");
    __builtin_amdgcn_s_barrier();

    int rd = 0;      // buffer holding chunk c
    int st = 2;      // buffer to stage chunk c+2 into
    for (int c = 0; c < 32; ++c) {
        // stage chunk c+2 (async; stays in flight across this iter's barrier)
        if (c + 2 < 32) {
            const short* gp = Wf + (size_t)(c + 2) * 6144 + wave * 1536 + lane * 8;
            short*       lp = sW + st * 6144 + wave * 1536;
            gll16(gp,        lp);
            gll16(gp +  512, lp +  512);
            gll16(gp + 1024, lp + 1024);
        }
        asm volatile("" ::: "memory");   // pin: stages before x loads
        // prefetch x slice c+2
        float4 n0 = b0, n1 = b1;
        if (c + 2 < 32) {
            n0 = *(const float4*)(xrow + (c + 2) * 32);
            n1 = *(const float4*)(xrow + (c + 2) * 32 + 4);
        }
        short8 af;
        af[0] = bf16_bits(a0.x); af[1] = bf16_bits(a0.y);
        af[2] = bf16_bits(a0.z); af[3] = bf16_bits(a0.w);
        af[4] = bf16_bits(a1.x); af[5] = bf16_bits(a1.y);
        af[6] = bf16_bits(a1.z); af[7] = bf16_bits(a1.w);
        const short* wsrc = sW + rd * 6144 + lane * 8;   // 16B/lane: conflict-free
        #pragma unroll
        for (int f = 0; f < 12; ++f) {
            const short8 bb = *(const short8*)(wsrc + f * 512);
            acc[f] = __builtin_amdgcn_mfma_f32_16x16x32_bf16(af, bb, acc[f], 0, 0, 0);
        }
        a0 = b0; a1 = b1; b0 = n0; b1 = n1;
        rd = (rd == 2) ? 0 : rd + 1;
        st = (st == 2) ? 0 : st + 1;
        // publish buf(c+1): counted wait, never drain.  lgkmcnt(0) closes the
        // WAR race (my ds_reads complete before anyone's next-stage lands).
        if (c < 30) {
            asm volatile("s_waitcnt vmcnt(7) lgkmcnt(0)" ::: "memory");
            __builtin_amdgcn_s_barrier();
        } else if (c == 30) {
            asm volatile("s_waitcnt vmcnt(2) lgkmcnt(0)" ::: "memory");
            __builtin_amdgcn_s_barrier();
        }
        // c == 31: no barrier here; the post-loop barrier protects epilogue.
    }
    __syncthreads();   // all waves done reading buf2 -> smem free for epilogue

    // ---- epilogue (aliased LDS) ----
    // NOTE: strip row stride MUST be >= 64 shorts (cols nt*16+l16 span 0..63).
    short (*eS)[2][16 * 72] = reinterpret_cast<short(*)[2][16 * 72]>(smem);
    short* eV = smem + 9216;                      // 64*80 = 5120 shorts

    // Q (wg=0) and K (wg=1): per-wave C->A/B-layout transform, no barrier
    #pragma unroll
    for (int wg = 0; wg < 2; ++wg) {
        const float* bias = wg ? bk : bq;
        #pragma unroll
        for (int nt = 0; nt < 4; ++nt) {
            const float bb = bias[nt * 16 + l16];
            #pragma unroll
            for (int r = 0; r < 4; ++r)
                eS[wave][wg][(quad * 4 + r) * 72 + nt * 16 + l16] =
                    bf16_bits(acc[wg * 4 + nt][r] + bb);
        }
    }
    #pragma unroll
    for (int wg = 0; wg < 2; ++wg) {
        const short8 v0 = *(const short8*)&eS[wave][wg][l16 * 72 + quad * 8];
        const short8 v1 = *(const short8*)&eS[wave][wg][l16 * 72 + 32 + quad * 8];
        if (wg == 0) {
            const size_t tg = (size_t)bx * 4 + wave;
            *(short8*)(Qf + (tg * 2 + 0) * 512 + lane * 8) = v0;
            *(short8*)(Qf + (tg * 2 + 1) * 512 + lane * 8) = v1;
        } else {
            *(short8*)(Kf + (((size_t)bx * 2 + 0) * 4 + wave) * 512 + lane * 8) = v0;
            *(short8*)(Kf + (((size_t)bx * 2 + 1) * 4 + wave) * 512 + lane * 8) = v1;
        }
    }

    // V: block-shared transpose (one barrier), fragment-order store
    #pragma unroll
    for (int nt = 0; nt < 4; ++nt) {
        const float bb = bv[nt * 16 + l16];
        #pragma unroll
        for (int r = 0; r < 4; ++r)
            eV[(nt * 16 + l16) * 80 + wave * 16 + quad * 4 + r] =
                bf16_bits(acc[8 + nt][r] + bb);
    }
    __syncthreads();
    #pragma unroll
    for (int s = 0; s < 2; ++s) {
        const int slot   = tid + s * 256;
        const int lane_s = slot & 63;
        const int u      = slot >> 6;            // 0..7
        const int th     = u >> 2, ntd = u & 3;
        const int q_s    = lane_s >> 4, l_s = lane_s & 15;
        const short8 v = *(const short8*)&eV[(ntd * 16 + l_s) * 80 + th * 32 + q_s * 8];
        *(short8*)(Vf + (((size_t)bx * 2 + th) * 4 + ntd) * 512 + lane_s * 8) = v;
    }
}

// ---------------------------------------------------------------------------
// Flash attention v5 + setprio: split-kt across 4 waves of one 16-row q strip
// + LDS merge.  grid (128, 16) x 256.  Loop is barrier-free (per-wave state).
// ---------------------------------------------------------------------------
__global__ __launch_bounds__(256) void attn_kernel(
    const short* __restrict__ Qf, const short* __restrict__ Kf,
    const short* __restrict__ Vf, float* __restrict__ out)
{
    const int tid  = threadIdx.x;
    const int wave = tid >> 6;
    const int lane = tid & 63;
    const int quad = lane >> 4;
    const int l16  = lane & 15;
    const int b    = blockIdx.y;
    const int bx   = blockIdx.x;
    const int qs   = (bx & 1) ? (127 - (bx >> 1)) : (bx >> 1);  // balance remap
    const int dTile = qs >> 2;
    const int tiles = dTile + 1;
    const int qoff  = (qs & 3) * 16;

    __shared__ __align__(16) unsigned char sm[17408 + 512];
    short* Ps   = (short*)sm;              // [4][16*72] per-wave strips (loop)
    float* Obuf = (float*)sm;              // [4][16][68]  (merge; aliases Ps)
    float* mb   = (float*)(sm + 17408);    // [4][16]
    float* lb   = mb + 64;                 // [4][16]

    // Q fragments, loaded once (coalesced)
    const size_t tg = (size_t)b * 128 + qs;
    const short8 qf0 = *(const short8*)(Qf + (tg * 2 + 0) * 512 + lane * 8);
    const short8 qf1 = *(const short8*)(Qf + (tg * 2 + 1) * 512 + lane * 8);

    f32x4 o[4] = {};
    float m_run[4], l_run[4];
    #pragma unroll
    for (int r = 0; r < 4; ++r) { m_run[r] = -INFINITY; l_run[r] = 0.0f; }

    const float C = 0.125f * 1.44269504088896340736f;  // scale * log2(e)

    for (int kt = wave; kt < tiles; kt += 4) {
        const short* ktile = Kf + (size_t)(b * 32 + kt) * 4096;
        const short* vtile = Vf + (size_t)(b * 32 + kt) * 4096;

        f32x4 s[4] = {};
        __builtin_amdgcn_s_setprio(1);
        #pragma unroll
        for (int nt = 0; nt < 4; ++nt) {
            const short8 kf0 = *(const short8*)(ktile + ((0 * 4 + nt) * 64 + lane) * 8);
            const short8 kf1 = *(const short8*)(ktile + ((1 * 4 + nt) * 64 + lane) * 8);
            s[nt] = __builtin_amdgcn_mfma_f32_16x16x32_bf16(qf0, kf0, s[nt], 0, 0, 0);
            s[nt] = __builtin_amdgcn_mfma_f32_16x16x32_bf16(qf1, kf1, s[nt], 0, 0, 0);
        }
        __builtin_amdgcn_s_setprio(0);

        if (kt == dTile) {
            #pragma unroll
            for (int nt = 0; nt < 4; ++nt) {
                const int kg = nt * 16 + l16;
                #pragma unroll
                for (int r = 0; r < 4; ++r) {
                    const int qg = qoff + quad * 4 + r;
                    s[nt][r] = (kg <= qg) ? s[nt][r] * C : -INFINITY;
                }
            }
        } else {
            #pragma unroll
            for (int nt = 0; nt < 4; ++nt)
                #pragma unroll
                for (int r = 0; r < 4; ++r) s[nt][r] *= C;
        }

        float rm[4];
        #pragma unroll
        for (int r = 0; r < 4; ++r)
            rm[r] = fmaxf(fmaxf(s[0][r], s[1][r]), fmaxf(s[2][r], s[3][r]));
        #pragma unroll
        for (int off = 1; off < 16; off <<= 1)
            #pragma unroll
            for (int r = 0; r < 4; ++r)
                rm[r] = fmaxf(rm[r], __shfl_xor(rm[r], off));

        float alpha[4];
        #pragma unroll
        for (int r = 0; r < 4; ++r) {
            const float mn = fmaxf(m_run[r], rm[r]);
            alpha[r] = exp2f(m_run[r] - mn);
            m_run[r] = mn;
        }

        float rs[4] = {0.f, 0.f, 0.f, 0.f};
        #pragma unroll
        for (int nt = 0; nt < 4; ++nt)
            #pragma unroll
            for (int r = 0; r < 4; ++r) {
                const float p = exp2f(s[nt][r] - m_run[r]);
                s[nt][r] = p;
                rs[r] += p;
            }
        #pragma unroll
        for (int off = 1; off < 16; off <<= 1)
            #pragma unroll
            for (int r = 0; r < 4; ++r)
                rs[r] += __shfl_xor(rs[r], off);
        #pragma unroll
        for (int r = 0; r < 4; ++r) l_run[r] = l_run[r] * alpha[r] + rs[r];

        #pragma unroll
        for (int r = 0; r < 4; ++r) {
            o[0][r] *= alpha[r]; o[1][r] *= alpha[r];
            o[2][r] *= alpha[r]; o[3][r] *= alpha[r];
        }

        // P: C-layout -> A-layout via per-wave-private strip (stride 72!)
        #pragma unroll
        for (int nt = 0; nt < 4; ++nt)
            #pragma unroll
            for (int r = 0; r < 4; ++r)
                Ps[wave * 1152 + (quad * 4 + r) * 72 + nt * 16 + l16] = bf16_bits(s[nt][r]);

        const short8 pf0 = *(const short8*)&Ps[wave * 1152 + l16 * 72 + quad * 8];
        const short8 pf1 = *(const short8*)&Ps[wave * 1152 + l16 * 72 + 32 + quad * 8];

        __builtin_amdgcn_s_setprio(1);
        #pragma unroll
        for (int nt = 0; nt < 4; ++nt) {
            const short8 vA = *(const short8*)(vtile + ((0 * 4 + nt) * 64 + lane) * 8);
            const short8 vB = *(const short8*)(vtile + ((1 * 4 + nt) * 64 + lane) * 8);
            o[nt] = __builtin_amdgcn_mfma_f32_16x16x32_bf16(pf0, vA, o[nt], 0, 0, 0);
            o[nt] = __builtin_amdgcn_mfma_f32_16x16x32_bf16(pf1, vB, o[nt], 0, 0, 0);
        }
        __builtin_amdgcn_s_setprio(0);
    }

    // ---- 4-wave merge ----
    if (l16 == 0) {
        #pragma unroll
        for (int r = 0; r < 4; ++r) mb[wave * 16 + quad * 4 + r] = m_run[r];
    }
    __syncthreads();   // all waves done with loop (Ps free); mb ready

    float fac[4];
    #pragma unroll
    for (int r = 0; r < 4; ++r) {
        const int row = quad * 4 + r;
        const float mg = fmaxf(fmaxf(mb[row], mb[16 + row]),
                               fmaxf(mb[32 + row], mb[48 + row]));
        fac[r] = exp2f(m_run[r] - mg);   // -inf -> 0 for idle waves
    }
    if (l16 == 0) {
        #pragma unroll
        for (int r = 0; r < 4; ++r) lb[wave * 16 + quad * 4 + r] = l_run[r] * fac[r];
    }
    #pragma unroll
    for (int nt = 0; nt < 4; ++nt)
        #pragma unroll
        for (int r = 0; r < 4; ++r)
            Obuf[wave * 1088 + (quad * 4 + r) * 68 + nt * 16 + l16] = o[nt][r] * fac[r];
    __syncthreads();

    // reduce 4 partials + store (coalesced float4)
    {
        const int row = tid >> 4;
        const int c0  = (tid & 15) * 4;
        const float lsum = lb[row] + lb[16 + row] + lb[32 + row] + lb[48 + row];
        float4 a = *(const float4*)&Obuf[0 * 1088 + row * 68 + c0];
        const float4 a1 = *(const float4*)&Obuf[1 * 1088 + row * 68 + c0];
        const float4 a2 = *(const float4*)&Obuf[2 * 1088 + row * 68 + c0];
        const float4 a3 = *(const float4*)&Obuf[3 * 1088 + row * 68 + c0];
        a.x += a1.x + a2.x + a3.x;  a.y += a1.y + a2.y + a3.y;
        a.z += a1.z + a2.z + a3.z;  a.w += a1.w + a2.w + a3.w;
        const float inv = 1.0f / lsum;
        float4 r4 = make_float4(a.x * inv, a.y * inv, a.z * inv, a.w * inv);
        *(float4*)(out + ((size_t)b * Seq + qs * 16 + row) * Hd + c0) = r4;
    }
}

// ---------------------------------------------------------------------------
extern "C" void kernel_launch(void* const* d_in, const int* in_sizes, int n_in,
                              void* d_out, int out_size, void* d_ws, size_t ws_size,
                              hipStream_t stream)
{
    const float* x  = (const float*)d_in[0];
    const float* Wq = (const float*)d_in[1];
    const float* bq = (const float*)d_in[2];
    const float* Wk = (const float*)d_in[3];
    const float* bk = (const float*)d_in[4];
    const float* Wv = (const float*)d_in[5];
    const float* bv = (const float*)d_in[6];
    float* out = (float*)d_out;

    short* Qf = (short*)d_ws;                    // 4 MB
    short* Kf = Qf + (size_t)Rows * Hd;          // 4 MB
    short* Vf = Kf + (size_t)Rows * Hd;          // 4 MB
    short* Wf = Vf + (size_t)Rows * Hd;          // 384 KB

    wt_prep<<<96, 256, 0, stream>>>(Wq, Wk, Wv, Wf);
    qkv_kernel<<<512, 256, 0, stream>>>(x, Wf, bq, bk, bv, Qf, Kf, Vf);
    attn_kernel<<<dim3(128, 16), 256, 0, stream>>>(Qf, Kf, Vf, out);
}

// Round 5
// 275.250 us; speedup vs baseline: 1.0497x; 1.0201x over previous
//
#include <hip/hip_runtime.h>
#include <hip/hip_bf16.h>
#include <math.h>

// B=16, S=2048, D=1024, HD=64
constexpr int Bsz  = 16;
constexpr int Seq  = 2048;
constexpr int Din  = 1024;
constexpr int Hd   = 64;
constexpr int Rows = Bsz * Seq;   // 32768

typedef short  short8 __attribute__((ext_vector_type(8)));
typedef float  f32x4  __attribute__((ext_vector_type(4)));

__device__ __forceinline__ short bf16_bits(float f) {
    __hip_bfloat16 h = __float2bfloat16(f);   // RNE
    return __builtin_bit_cast(short, h);
}

// async global->LDS, 16B per lane (dest = lds base + lane*16)
typedef __attribute__((address_space(1))) const void gvoid_t;
typedef __attribute__((address_space(3))) void lvoid_t;
__device__ __forceinline__ void gll16(const void* g, void* l) {
    __builtin_amdgcn_global_load_lds((gvoid_t*)g, (lvoid_t*)l, 16, 0, 0);
}

// ---------------------------------------------------------------------------
// Wf fragment order: [chunk k/32][f = wg*4+nt][lane = quad*16+l16][j 0..8)
//   holds W_wg[k = chunk*32 + quad*8 + j][n = nt*16 + l16]
// ---------------------------------------------------------------------------
__global__ __launch_bounds__(256) void wt_prep(
    const float* __restrict__ Wq, const float* __restrict__ Wk,
    const float* __restrict__ Wv, short* __restrict__ Wf)
{
    const int u     = blockIdx.x * 256 + threadIdx.x;   // 0..24575
    const int chunk = u / 768;
    const int rem   = u - chunk * 768;
    const int f     = rem >> 6;
    const int lane  = rem & 63;
    const int wg    = f >> 2, nt = f & 3;
    const int quad  = lane >> 4, l16 = lane & 15;
    const float* W  = (wg == 0) ? Wq : (wg == 1) ? Wk : Wv;
    const int k0 = chunk * 32 + quad * 8;
    const int n  = nt * 16 + l16;
    short8 v;
    #pragma unroll
    for (int j = 0; j < 8; ++j) v[j] = bf16_bits(W[(size_t)(k0 + j) * Hd + n]);
    *(short8*)(Wf + (size_t)u * 8) = v;
}

// ---------------------------------------------------------------------------
// QKV v10: v9 pipeline (triple-buffered Wf stage-2-ahead, x reg prefetch
// depth 2, counted vmcnt: never drain in-loop) with COMPILE-TIME buffer
// indices: K-loop manually unrolled x3 so RD/ST are template constants ->
// ds_read offsets fold to immediates, stage LDS dests are constant bases.
// Steady-state barrier: s_waitcnt vmcnt(7) lgkmcnt(0); s_barrier
//   (7 newest in flight = {x(c+1):2, st(c+2):3, x(c+2):2}; publishes
//    buf(c+1) via in-order vmcnt retirement, keeps 2-iter window on x.)
// ---------------------------------------------------------------------------
template<int RD, int ST, bool STAGE, bool PREF>
__device__ __forceinline__ void qkv_step(
    const short*& wf_stage, short* sW, int wave, int lane,
    const float*& xpf,
    float4& a0, float4& a1, float4& b0, float4& b1,
    f32x4 (&acc)[12])
{
    if (STAGE) {
        short* lp = sW + ST * 6144 + wave * 1536;
        gll16(wf_stage,        lp);
        gll16(wf_stage +  512, lp +  512);
        gll16(wf_stage + 1024, lp + 1024);
        wf_stage += 6144;
    }
    asm volatile("" ::: "memory");   // pin: stages issued before x loads
    float4 n0, n1;
    if (PREF) {
        n0 = *(const float4*)xpf;
        n1 = *(const float4*)(xpf + 4);
        xpf += 32;
    }
    short8 af;
    af[0] = bf16_bits(a0.x); af[1] = bf16_bits(a0.y);
    af[2] = bf16_bits(a0.z); af[3] = bf16_bits(a0.w);
    af[4] = bf16_bits(a1.x); af[5] = bf16_bits(a1.y);
    af[6] = bf16_bits(a1.z); af[7] = bf16_bits(a1.w);
    const short* wsrc = sW + RD * 6144 + lane * 8;   // RD*6144: immediate
    #pragma unroll
    for (int f = 0; f < 12; ++f) {
        const short8 bb = *(const short8*)(wsrc + f * 512);
        acc[f] = __builtin_amdgcn_mfma_f32_16x16x32_bf16(af, bb, acc[f], 0, 0, 0);
    }
    a0 = b0; a1 = b1;
    if (PREF) { b0 = n0; b1 = n1; }
}

#define QKV_BAR(N)                                                      \
    asm volatile("s_waitcnt vmcnt(" #N ") lgkmcnt(0)" ::: "memory");    \
    __builtin_amdgcn_s_barrier();

__global__ __launch_bounds__(256) void qkv_kernel(
    const float* __restrict__ x,
    const short* __restrict__ Wf,
    const float* __restrict__ bq, const float* __restrict__ bk,
    const float* __restrict__ bv,
    short* __restrict__ Qf, short* __restrict__ Kf, short* __restrict__ Vf)
{
    const int tid  = threadIdx.x;
    const int wave = tid >> 6;
    const int lane = tid & 63;
    const int quad = lane >> 4;
    const int l16  = lane & 15;
    const int bx   = blockIdx.x;
    const int m0   = bx * 64;

    // 36864 B LDS: triple buffer sW[3][6144] shorts; epilogue aliases
    // smem[0..14336) -- protected by the post-loop barrier.
    __shared__ __align__(16) short smem[18432];
    short* sW = smem;

    const float* xrow = x + (size_t)(m0 + wave * 16 + l16) * Din + quad * 8;

    f32x4 acc[12] = {};

    // ---- prologue: stage chunks 0,1 -> buf0,buf1; x(0),x(1) -> regs ----
    {
        const short* gp = Wf + wave * 1536 + lane * 8;
        short*       lp = sW + wave * 1536;
        gll16(gp,        lp);
        gll16(gp +  512, lp +  512);
        gll16(gp + 1024, lp + 1024);
        const short* gp1 = gp + 6144;
        short*       lp1 = lp + 6144;
        gll16(gp1,        lp1);
        gll16(gp1 +  512, lp1 +  512);
        gll16(gp1 + 1024, lp1 + 1024);
    }
    asm volatile("" ::: "memory");   // pin: stages issued before x loads
    float4 a0 = *(const float4*)(xrow);
    float4 a1 = *(const float4*)(xrow + 4);
    float4 b0 = *(const float4*)(xrow + 32);
    float4 b1 = *(const float4*)(xrow + 36);
    // need st(0) done; newer ops = st(1):3 + x(0):2 + x(1):2 = 7
    QKV_BAR(7)

    const short* wf_stage = Wf + 2 * 6144 + wave * 1536 + lane * 8;  // chunk c+2
    const float* xpf      = xrow + 2 * 32;                           // x(c+2)

    #pragma unroll 1
    for (int c3 = 0; c3 < 30; c3 += 3) {
        qkv_step<0, 2, true, true>(wf_stage, sW, wave, lane, xpf, a0, a1, b0, b1, acc);
        QKV_BAR(7)
        qkv_step<1, 0, true, true>(wf_stage, sW, wave, lane, xpf, a0, a1, b0, b1, acc);
        QKV_BAR(7)
        qkv_step<2, 1, true, true>(wf_stage, sW, wave, lane, xpf, a0, a1, b0, b1, acc);
        QKV_BAR(7)
    }
    // c = 30 (rd=0): nothing left to stage/prefetch; need st(31): newer = x(31):2
    qkv_step<0, 0, false, false>(wf_stage, sW, wave, lane, xpf, a0, a1, b0, b1, acc);
    QKV_BAR(2)
    // c = 31 (rd=1): last compute; no barrier (post-loop syncthreads follows)
    qkv_step<1, 0, false, false>(wf_stage, sW, wave, lane, xpf, a0, a1, b0, b1, acc);

    __syncthreads();   // all waves done reading buf1 -> smem free for epilogue

    // ---- epilogue (aliased LDS) ----
    // NOTE: strip row stride MUST be >= 64 shorts (cols nt*16+l16 span 0..63).
    short (*eS)[2][16 * 72] = reinterpret_cast<short(*)[2][16 * 72]>(smem);
    short* eV = smem + 9216;                      // 64*80 = 5120 shorts

    // Q (wg=0) and K (wg=1): per-wave C->A/B-layout transform, no barrier
    #pragma unroll
    for (int wg = 0; wg < 2; ++wg) {
        const float* bias = wg ? bk : bq;
        #pragma unroll
        for (int nt = 0; nt < 4; ++nt) {
            const float bb = bias[nt * 16 + l16];
            #pragma unroll
            for (int r = 0; r < 4; ++r)
                eS[wave][wg][(quad * 4 + r) * 72 + nt * 16 + l16] =
                    bf16_bits(acc[wg * 4 + nt][r] + bb);
        }
    }
    #pragma unroll
    for (int wg = 0; wg < 2; ++wg) {
        const short8 v0 = *(const short8*)&eS[wave][wg][l16 * 72 + quad * 8];
        const short8 v1 = *(const short8*)&eS[wave][wg][l16 * 72 + 32 + quad * 8];
        if (wg == 0) {
            const size_t tg = (size_t)bx * 4 + wave;
            *(short8*)(Qf + (tg * 2 + 0) * 512 + lane * 8) = v0;
            *(short8*)(Qf + (tg * 2 + 1) * 512 + lane * 8) = v1;
        } else {
            *(short8*)(Kf + (((size_t)bx * 2 + 0) * 4 + wave) * 512 + lane * 8) = v0;
            *(short8*)(Kf + (((size_t)bx * 2 + 1) * 4 + wave) * 512 + lane * 8) = v1;
        }
    }

    // V: block-shared transpose (one barrier), fragment-order store
    #pragma unroll
    for (int nt = 0; nt < 4; ++nt) {
        const float bb = bv[nt * 16 + l16];
        #pragma unroll
        for (int r = 0; r < 4; ++r)
            eV[(nt * 16 + l16) * 80 + wave * 16 + quad * 4 + r] =
                bf16_bits(acc[8 + nt][r] + bb);
    }
    __syncthreads();
    #pragma unroll
    for (int s = 0; s < 2; ++s) {
        const int slot   = tid + s * 256;
        const int lane_s = slot & 63;
        const int u      = slot >> 6;            // 0..7
        const int th     = u >> 2, ntd = u & 3;
        const int q_s    = lane_s >> 4, l_s = lane_s & 15;
        const short8 v = *(const short8*)&eV[(ntd * 16 + l_s) * 80 + th * 32 + q_s * 8];
        *(short8*)(Vf + (((size_t)bx * 2 + th) * 4 + ntd) * 512 + lane_s * 8) = v;
    }
}

// ---------------------------------------------------------------------------
// Flash attention v5 + setprio: split-kt across 4 waves of one 16-row q strip
// + LDS merge.  grid (128, 16) x 256.  Loop is barrier-free (per-wave state).
// ---------------------------------------------------------------------------
__global__ __launch_bounds__(256) void attn_kernel(
    const short* __restrict__ Qf, const short* __restrict__ Kf,
    const short* __restrict__ Vf, float* __restrict__ out)
{
    const int tid  = threadIdx.x;
    const int wave = tid >> 6;
    const int lane = tid & 63;
    const int quad = lane >> 4;
    const int l16  = lane & 15;
    const int b    = blockIdx.y;
    const int bx   = blockIdx.x;
    const int qs   = (bx & 1) ? (127 - (bx >> 1)) : (bx >> 1);  // balance remap
    const int dTile = qs >> 2;
    const int tiles = dTile + 1;
    const int qoff  = (qs & 3) * 16;

    __shared__ __align__(16) unsigned char sm[17408 + 512];
    short* Ps   = (short*)sm;              // [4][16*72] per-wave strips (loop)
    float* Obuf = (float*)sm;              // [4][16][68]  (merge; aliases Ps)
    float* mb   = (float*)(sm + 17408);    // [4][16]
    float* lb   = mb + 64;                 // [4][16]

    // Q fragments, loaded once (coalesced)
    const size_t tg = (size_t)b * 128 + qs;
    const short8 qf0 = *(const short8*)(Qf + (tg * 2 + 0) * 512 + lane * 8);
    const short8 qf1 = *(const short8*)(Qf + (tg * 2 + 1) * 512 + lane * 8);

    f32x4 o[4] = {};
    float m_run[4], l_run[4];
    #pragma unroll
    for (int r = 0; r < 4; ++r) { m_run[r] = -INFINITY; l_run[r] = 0.0f; }

    const float C = 0.125f * 1.44269504088896340736f;  // scale * log2(e)

    for (int kt = wave; kt < tiles; kt += 4) {
        const short* ktile = Kf + (size_t)(b * 32 + kt) * 4096;
        const short* vtile = Vf + (size_t)(b * 32 + kt) * 4096;

        f32x4 s[4] = {};
        __builtin_amdgcn_s_setprio(1);
        #pragma unroll
        for (int nt = 0; nt < 4; ++nt) {
            const short8 kf0 = *(const short8*)(ktile + ((0 * 4 + nt) * 64 + lane) * 8);
            const short8 kf1 = *(const short8*)(ktile + ((1 * 4 + nt) * 64 + lane) * 8);
            s[nt] = __builtin_amdgcn_mfma_f32_16x16x32_bf16(qf0, kf0, s[nt], 0, 0, 0);
            s[nt] = __builtin_amdgcn_mfma_f32_16x16x32_bf16(qf1, kf1, s[nt], 0, 0, 0);
        }
        __builtin_amdgcn_s_setprio(0);

        if (kt == dTile) {
            #pragma unroll
            for (int nt = 0; nt < 4; ++nt) {
                const int kg = nt * 16 + l16;
                #pragma unroll
                for (int r = 0; r < 4; ++r) {
                    const int qg = qoff + quad * 4 + r;
                    s[nt][r] = (kg <= qg) ? s[nt][r] * C : -INFINITY;
                }
            }
        } else {
            #pragma unroll
            for (int nt = 0; nt < 4; ++nt)
                #pragma unroll
                for (int r = 0; r < 4; ++r) s[nt][r] *= C;
        }

        float rm[4];
        #pragma unroll
        for (int r = 0; r < 4; ++r)
            rm[r] = fmaxf(fmaxf(s[0][r], s[1][r]), fmaxf(s[2][r], s[3][r]));
        #pragma unroll
        for (int off = 1; off < 16; off <<= 1)
            #pragma unroll
            for (int r = 0; r < 4; ++r)
                rm[r] = fmaxf(rm[r], __shfl_xor(rm[r], off));

        float alpha[4];
        #pragma unroll
        for (int r = 0; r < 4; ++r) {
            const float mn = fmaxf(m_run[r], rm[r]);
            alpha[r] = exp2f(m_run[r] - mn);
            m_run[r] = mn;
        }

        float rs[4] = {0.f, 0.f, 0.f, 0.f};
        #pragma unroll
        for (int nt = 0; nt < 4; ++nt)
            #pragma unroll
            for (int r = 0; r < 4; ++r) {
                const float p = exp2f(s[nt][r] - m_run[r]);
                s[nt][r] = p;
                rs[r] += p;
            }
        #pragma unroll
        for (int off = 1; off < 16; off <<= 1)
            #pragma unroll
            for (int r = 0; r < 4; ++r)
                rs[r] += __shfl_xor(rs[r], off);
        #pragma unroll
        for (int r = 0; r < 4; ++r) l_run[r] = l_run[r] * alpha[r] + rs[r];

        #pragma unroll
        for (int r = 0; r < 4; ++r) {
            o[0][r] *= alpha[r]; o[1][r] *= alpha[r];
            o[2][r] *= alpha[r]; o[3][r] *= alpha[r];
        }

        // P: C-layout -> A-layout via per-wave-private strip (stride 72!)
        #pragma unroll
        for (int nt = 0; nt < 4; ++nt)
            #pragma unroll
            for (int r = 0; r < 4; ++r)
                Ps[wave * 1152 + (quad * 4 + r) * 72 + nt * 16 + l16] = bf16_bits(s[nt][r]);

        const short8 pf0 = *(const short8*)&Ps[wave * 1152 + l16 * 72 + quad * 8];
        const short8 pf1 = *(const short8*)&Ps[wave * 1152 + l16 * 72 + 32 + quad * 8];

        __builtin_amdgcn_s_setprio(1);
        #pragma unroll
        for (int nt = 0; nt < 4; ++nt) {
            const short8 vA = *(const short8*)(vtile + ((0 * 4 + nt) * 64 + lane) * 8);
            const short8 vB = *(const short8*)(vtile + ((1 * 4 + nt) * 64 + lane) * 8);
            o[nt] = __builtin_amdgcn_mfma_f32_16x16x32_bf16(pf0, vA, o[nt], 0, 0, 0);
            o[nt] = __builtin_amdgcn_mfma_f32_16x16x32_bf16(pf1, vB, o[nt], 0, 0, 0);
        }
        __builtin_amdgcn_s_setprio(0);
    }

    // ---- 4-wave merge ----
    if (l16 == 0) {
        #pragma unroll
        for (int r = 0; r < 4; ++r) mb[wave * 16 + quad * 4 + r] = m_run[r];
    }
    __syncthreads();   // all waves done with loop (Ps free); mb ready

    float fac[4];
    #pragma unroll
    for (int r = 0; r < 4; ++r) {
        const int row = quad * 4 + r;
        const float mg = fmaxf(fmaxf(mb[row], mb[16 + row]),
                               fmaxf(mb[32 + row], mb[48 + row]));
        fac[r] = exp2f(m_run[r] - mg);   // -inf -> 0 for idle waves
    }
    if (l16 == 0) {
        #pragma unroll
        for (int r = 0; r < 4; ++r) lb[wave * 16 + quad * 4 + r] = l_run[r] * fac[r];
    }
    #pragma unroll
    for (int nt = 0; nt < 4; ++nt)
        #pragma unroll
        for (int r = 0; r < 4; ++r)
            Obuf[wave * 1088 + (quad * 4 + r) * 68 + nt * 16 + l16] = o[nt][r] * fac[r];
    __syncthreads();

    // reduce 4 partials + store (coalesced float4)
    {
        const int row = tid >> 4;
        const int c0  = (tid & 15) * 4;
        const float lsum = lb[row] + lb[16 + row] + lb[32 + row] + lb[48 + row];
        float4 a = *(const float4*)&Obuf[0 * 1088 + row * 68 + c0];
        const float4 a1 = *(const float4*)&Obuf[1 * 1088 + row * 68 + c0];
        const float4 a2 = *(const float4*)&Obuf[2 * 1088 + row * 68 + c0];
        const float4 a3 = *(const float4*)&Obuf[3 * 1088 + row * 68 + c0];
        a.x += a1.x + a2.x + a3.x;  a.y += a1.y + a2.y + a3.y;
        a.z += a1.z + a2.z + a3.z;  a.w += a1.w + a2.w + a3.w;
        const float inv = 1.0f / lsum;
        float4 r4 = make_float4(a.x * inv, a.y * inv, a.z * inv, a.w * inv);
        *(float4*)(out + ((size_t)b * Seq + qs * 16 + row) * Hd + c0) = r4;
    }
}

// ---------------------------------------------------------------------------
extern "C" void kernel_launch(void* const* d_in, const int* in_sizes, int n_in,
                              void* d_out, int out_size, void* d_ws, size_t ws_size,
                              hipStream_t stream)
{
    const float* x  = (const float*)d_in[0];
    const float* Wq = (const float*)d_in[1];
    const float* bq = (const float*)d_in[2];
    const float* Wk = (const float*)d_in[3];
    const float* bk = (const float*)d_in[4];
    const float* Wv = (const float*)d_in[5];
    const float* bv = (const float*)d_in[6];
    float* out = (float*)d_out;

    short* Qf = (short*)d_ws;                    // 4 MB
    short* Kf = Qf + (size_t)Rows * Hd;          // 4 MB
    short* Vf = Kf + (size_t)Rows * Hd;          // 4 MB
    short* Wf = Vf + (size_t)Rows * Hd;          // 384 KB

    wt_prep<<<96, 256, 0, stream>>>(Wq, Wk, Wv, Wf);
    qkv_kernel<<<512, 256, 0, stream>>>(x, Wf, bq, bk, bv, Qf, Kf, Vf);
    attn_kernel<<<dim3(128, 16), 256, 0, stream>>>(Qf, Kf, Vf, out);
}

// Round 6
// 273.499 us; speedup vs baseline: 1.0564x; 1.0064x over previous
//
#include <hip/hip_runtime.h>
#include <hip/hip_bf16.h>
#include <math.h>

// B=16, S=2048, D=1024, HD=64
constexpr int Bsz  = 16;
constexpr int Seq  = 2048;
constexpr int Din  = 1024;
constexpr int Hd   = 64;
constexpr int Rows = Bsz * Seq;   // 32768

typedef short  short8 __attribute__((ext_vector_type(8)));
typedef float  f32x4  __attribute__((ext_vector_type(4)));

__device__ __forceinline__ short bf16_bits(float f) {
    __hip_bfloat16 h = __float2bfloat16(f);   // RNE
    return __builtin_bit_cast(short, h);
}

// async global->LDS, 16B per lane (dest = lds base + lane*16)
typedef __attribute__((address_space(1))) const void gvoid_t;
typedef __attribute__((address_space(3))) void lvoid_t;
__device__ __forceinline__ void gll16(const void* g, void* l) {
    __builtin_amdgcn_global_load_lds((gvoid_t*)g, (lvoid_t*)l, 16, 0, 0);
}

// ---------------------------------------------------------------------------
// Wf fragment order: [chunk k/32][f = wg*4+nt][lane = quad*16+l16][j 0..8)
//   holds W_wg[k = chunk*32 + quad*8 + j][n = nt*16 + l16]
// ---------------------------------------------------------------------------
__global__ __launch_bounds__(256) void wt_prep(
    const float* __restrict__ Wq, const float* __restrict__ Wk,
    const float* __restrict__ Wv, short* __restrict__ Wf)
{
    const int u     = blockIdx.x * 256 + threadIdx.x;   // 0..24575
    const int chunk = u / 768;
    const int rem   = u - chunk * 768;
    const int f     = rem >> 6;
    const int lane  = rem & 63;
    const int wg    = f >> 2, nt = f & 3;
    const int quad  = lane >> 4, l16 = lane & 15;
    const float* W  = (wg == 0) ? Wq : (wg == 1) ? Wk : Wv;
    const int k0 = chunk * 32 + quad * 8;
    const int n  = nt * 16 + l16;
    short8 v;
    #pragma unroll
    for (int j = 0; j < 8; ++j) v[j] = bf16_bits(W[(size_t)(k0 + j) * Hd + n]);
    *(short8*)(Wf + (size_t)u * 8) = v;
}

// ---------------------------------------------------------------------------
// QKV v10 (unchanged from best-known): triple-buffered Wf stage-2-ahead,
// x reg prefetch depth 2, counted vmcnt, compile-time buffer indices.
// ---------------------------------------------------------------------------
template<int RD, int ST, bool STAGE, bool PREF>
__device__ __forceinline__ void qkv_step(
    const short*& wf_stage, short* sW, int wave, int lane,
    const float*& xpf,
    float4& a0, float4& a1, float4& b0, float4& b1,
    f32x4 (&acc)[12])
{
    if (STAGE) {
        short* lp = sW + ST * 6144 + wave * 1536;
        gll16(wf_stage,        lp);
        gll16(wf_stage +  512, lp +  512);
        gll16(wf_stage + 1024, lp + 1024);
        wf_stage += 6144;
    }
    asm volatile("" ::: "memory");   // pin: stages issued before x loads
    float4 n0, n1;
    if (PREF) {
        n0 = *(const float4*)xpf;
        n1 = *(const float4*)(xpf + 4);
        xpf += 32;
    }
    short8 af;
    af[0] = bf16_bits(a0.x); af[1] = bf16_bits(a0.y);
    af[2] = bf16_bits(a0.z); af[3] = bf16_bits(a0.w);
    af[4] = bf16_bits(a1.x); af[5] = bf16_bits(a1.y);
    af[6] = bf16_bits(a1.z); af[7] = bf16_bits(a1.w);
    const short* wsrc = sW + RD * 6144 + lane * 8;   // RD*6144: immediate
    #pragma unroll
    for (int f = 0; f < 12; ++f) {
        const short8 bb = *(const short8*)(wsrc + f * 512);
        acc[f] = __builtin_amdgcn_mfma_f32_16x16x32_bf16(af, bb, acc[f], 0, 0, 0);
    }
    a0 = b0; a1 = b1;
    if (PREF) { b0 = n0; b1 = n1; }
}

#define QKV_BAR(N)                                                      \
    asm volatile("s_waitcnt vmcnt(" #N ") lgkmcnt(0)" ::: "memory");    \
    __builtin_amdgcn_s_barrier();

__global__ __launch_bounds__(256) void qkv_kernel(
    const float* __restrict__ x,
    const short* __restrict__ Wf,
    const float* __restrict__ bq, const float* __restrict__ bk,
    const float* __restrict__ bv,
    short* __restrict__ Qf, short* __restrict__ Kf, short* __restrict__ Vf)
{
    const int tid  = threadIdx.x;
    const int wave = tid >> 6;
    const int lane = tid & 63;
    const int quad = lane >> 4;
    const int l16  = lane & 15;
    const int bx   = blockIdx.x;
    const int m0   = bx * 64;

    // 36864 B LDS: triple buffer sW[3][6144] shorts; epilogue aliases
    // smem[0..14336) -- protected by the post-loop barrier.
    __shared__ __align__(16) short smem[18432];
    short* sW = smem;

    const float* xrow = x + (size_t)(m0 + wave * 16 + l16) * Din + quad * 8;

    f32x4 acc[12] = {};

    // ---- prologue: stage chunks 0,1 -> buf0,buf1; x(0),x(1) -> regs ----
    {
        const short* gp = Wf + wave * 1536 + lane * 8;
        short*       lp = sW + wave * 1536;
        gll16(gp,        lp);
        gll16(gp +  512, lp +  512);
        gll16(gp + 1024, lp + 1024);
        const short* gp1 = gp + 6144;
        short*       lp1 = lp + 6144;
        gll16(gp1,        lp1);
        gll16(gp1 +  512, lp1 +  512);
        gll16(gp1 + 1024, lp1 + 1024);
    }
    asm volatile("" ::: "memory");   // pin: stages issued before x loads
    float4 a0 = *(const float4*)(xrow);
    float4 a1 = *(const float4*)(xrow + 4);
    float4 b0 = *(const float4*)(xrow + 32);
    float4 b1 = *(const float4*)(xrow + 36);
    // need st(0) done; newer ops = st(1):3 + x(0):2 + x(1):2 = 7
    QKV_BAR(7)

    const short* wf_stage = Wf + 2 * 6144 + wave * 1536 + lane * 8;  // chunk c+2
    const float* xpf      = xrow + 2 * 32;                           // x(c+2)

    #pragma unroll 1
    for (int c3 = 0; c3 < 30; c3 += 3) {
        qkv_step<0, 2, true, true>(wf_stage, sW, wave, lane, xpf, a0, a1, b0, b1, acc);
        QKV_BAR(7)
        qkv_step<1, 0, true, true>(wf_stage, sW, wave, lane, xpf, a0, a1, b0, b1, acc);
        QKV_BAR(7)
        qkv_step<2, 1, true, true>(wf_stage, sW, wave, lane, xpf, a0, a1, b0, b1, acc);
        QKV_BAR(7)
    }
    // c = 30 (rd=0): nothing left to stage/prefetch; need st(31): newer = x(31):2
    qkv_step<0, 0, false, false>(wf_stage, sW, wave, lane, xpf, a0, a1, b0, b1, acc);
    QKV_BAR(2)
    // c = 31 (rd=1): last compute; no barrier (post-loop syncthreads follows)
    qkv_step<1, 0, false, false>(wf_stage, sW, wave, lane, xpf, a0, a1, b0, b1, acc);

    __syncthreads();   // all waves done reading buf1 -> smem free for epilogue

    // ---- epilogue (aliased LDS) ----
    // NOTE: strip row stride MUST be >= 64 shorts (cols nt*16+l16 span 0..63).
    short (*eS)[2][16 * 72] = reinterpret_cast<short(*)[2][16 * 72]>(smem);
    short* eV = smem + 9216;                      // 64*80 = 5120 shorts

    // Q (wg=0) and K (wg=1): per-wave C->A/B-layout transform, no barrier
    #pragma unroll
    for (int wg = 0; wg < 2; ++wg) {
        const float* bias = wg ? bk : bq;
        #pragma unroll
        for (int nt = 0; nt < 4; ++nt) {
            const float bb = bias[nt * 16 + l16];
            #pragma unroll
            for (int r = 0; r < 4; ++r)
                eS[wave][wg][(quad * 4 + r) * 72 + nt * 16 + l16] =
                    bf16_bits(acc[wg * 4 + nt][r] + bb);
        }
    }
    #pragma unroll
    for (int wg = 0; wg < 2; ++wg) {
        const short8 v0 = *(const short8*)&eS[wave][wg][l16 * 72 + quad * 8];
        const short8 v1 = *(const short8*)&eS[wave][wg][l16 * 72 + 32 + quad * 8];
        if (wg == 0) {
            const size_t tg = (size_t)bx * 4 + wave;
            *(short8*)(Qf + (tg * 2 + 0) * 512 + lane * 8) = v0;
            *(short8*)(Qf + (tg * 2 + 1) * 512 + lane * 8) = v1;
        } else {
            *(short8*)(Kf + (((size_t)bx * 2 + 0) * 4 + wave) * 512 + lane * 8) = v0;
            *(short8*)(Kf + (((size_t)bx * 2 + 1) * 4 + wave) * 512 + lane * 8) = v1;
        }
    }

    // V: block-shared transpose (one barrier), fragment-order store
    #pragma unroll
    for (int nt = 0; nt < 4; ++nt) {
        const float bb = bv[nt * 16 + l16];
        #pragma unroll
        for (int r = 0; r < 4; ++r)
            eV[(nt * 16 + l16) * 80 + wave * 16 + quad * 4 + r] =
                bf16_bits(acc[8 + nt][r] + bb);
    }
    __syncthreads();
    #pragma unroll
    for (int s = 0; s < 2; ++s) {
        const int slot   = tid + s * 256;
        const int lane_s = slot & 63;
        const int u      = slot >> 6;            // 0..7
        const int th     = u >> 2, ntd = u & 3;
        const int q_s    = lane_s >> 4, l_s = lane_s & 15;
        const short8 v = *(const short8*)&eV[(ntd * 16 + l_s) * 80 + th * 32 + q_s * 8];
        *(short8*)(Vf + (((size_t)bx * 2 + th) * 4 + ntd) * 512 + lane_s * 8) = v;
    }
}

// ---------------------------------------------------------------------------
// Flash attention v6: 64 q-rows per block (4 waves, one 16-row strip each,
// ALL sharing the same tile range 0..qb), K/V tiles staged ONCE per block
// into double-buffered LDS via global_load_lds (stage-1-ahead, one barrier
// per tile).  No split-kt, no merge.  grid (32, 16) x 256.
// K/V cache traffic: 540 MB -> 135 MB vs v5.
// Balance: same-CU pair is (id, id+256) = same bx, by+8 -> flip qb on by>=8
// so each CU's two blocks sum to 33 tiles.
// ---------------------------------------------------------------------------
__global__ __launch_bounds__(256) void attn_kernel(
    const short* __restrict__ Qf, const short* __restrict__ Kf,
    const short* __restrict__ Vf, float* __restrict__ out)
{
    const int tid  = threadIdx.x;
    const int wave = tid >> 6;
    const int lane = tid & 63;
    const int quad = lane >> 4;
    const int l16  = lane & 15;
    const int b    = blockIdx.y;
    const int bx   = blockIdx.x;            // 0..31
    const int qb0  = (bx & 1) ? (31 - (bx >> 1)) : (bx >> 1);
    const int qb   = (blockIdx.y & 8) ? (31 - qb0) : qb0;   // per-CU pairing
    const int ntiles = qb + 1;
    const int qs   = qb * 4 + wave;         // this wave's 16-row strip
    const int qoff = wave * 16;             // q offset within diagonal tile

    // LDS: K/V double buffer 2 x (4096 K + 4096 V) shorts = 32768 B,
    //      Ps 4 x 1152 shorts = 9216 B.  Obuf (epilogue) aliases kv.
    __shared__ __align__(16) short kv[2][8192];
    __shared__ __align__(16) short Ps[4][1152];
    float* Obuf = (float*)kv;               // [4][16*68] f32 = 17408 B

    // Q fragments, loaded once (coalesced)
    const size_t tg = (size_t)b * 128 + qs;
    const short8 qf0 = *(const short8*)(Qf + (tg * 2 + 0) * 512 + lane * 8);
    const short8 qf1 = *(const short8*)(Qf + (tg * 2 + 1) * 512 + lane * 8);

    const short* kbase = Kf + (size_t)b * 32 * 4096;
    const short* vbase = Vf + (size_t)b * 32 * 4096;

    f32x4 o[4] = {};
    float m_run[4], l_run[4];
    #pragma unroll
    for (int r = 0; r < 4; ++r) { m_run[r] = -INFINITY; l_run[r] = 0.0f; }

    const float C = 0.125f * 1.44269504088896340736f;  // scale * log2(e)

    // ---- prologue: stage tile 0 (each wave stages 1/4 of K and of V) ----
    {
        const short* gk = kbase + wave * 1024 + lane * 8;
        const short* gv = vbase + wave * 1024 + lane * 8;
        short* lk = &kv[0][0]    + wave * 1024;
        short* lv = &kv[0][4096] + wave * 1024;
        gll16(gk,       lk);
        gll16(gk + 512, lk + 512);
        gll16(gv,       lv);
        gll16(gv + 512, lv + 512);
    }
    __syncthreads();

    for (int kt = 0; kt < ntiles; ++kt) {
        const int cur = kt & 1;
        // stage tile kt+1 into the other buffer (async; drains at barrier)
        if (kt + 1 < ntiles) {
            const short* gk = kbase + (size_t)(kt + 1) * 4096 + wave * 1024 + lane * 8;
            const short* gv = vbase + (size_t)(kt + 1) * 4096 + wave * 1024 + lane * 8;
            short* lk = &kv[cur ^ 1][0]    + wave * 1024;
            short* lv = &kv[cur ^ 1][4096] + wave * 1024;
            gll16(gk,       lk);
            gll16(gk + 512, lk + 512);
            gll16(gv,       lv);
            gll16(gv + 512, lv + 512);
        }
        const short* ktile = &kv[cur][0];
        const short* vtile = &kv[cur][4096];

        f32x4 s[4] = {};
        __builtin_amdgcn_s_setprio(1);
        #pragma unroll
        for (int nt = 0; nt < 4; ++nt) {
            const short8 kf0 = *(const short8*)(ktile + ((0 * 4 + nt) * 64 + lane) * 8);
            const short8 kf1 = *(const short8*)(ktile + ((1 * 4 + nt) * 64 + lane) * 8);
            s[nt] = __builtin_amdgcn_mfma_f32_16x16x32_bf16(qf0, kf0, s[nt], 0, 0, 0);
            s[nt] = __builtin_amdgcn_mfma_f32_16x16x32_bf16(qf1, kf1, s[nt], 0, 0, 0);
        }
        __builtin_amdgcn_s_setprio(0);

        if (kt == qb) {
            #pragma unroll
            for (int nt = 0; nt < 4; ++nt) {
                const int kg = nt * 16 + l16;
                #pragma unroll
                for (int r = 0; r < 4; ++r) {
                    const int qg = qoff + quad * 4 + r;
                    s[nt][r] = (kg <= qg) ? s[nt][r] * C : -INFINITY;
                }
            }
        } else {
            #pragma unroll
            for (int nt = 0; nt < 4; ++nt)
                #pragma unroll
                for (int r = 0; r < 4; ++r) s[nt][r] *= C;
        }

        float rm[4];
        #pragma unroll
        for (int r = 0; r < 4; ++r)
            rm[r] = fmaxf(fmaxf(s[0][r], s[1][r]), fmaxf(s[2][r], s[3][r]));
        #pragma unroll
        for (int off = 1; off < 16; off <<= 1)
            #pragma unroll
            for (int r = 0; r < 4; ++r)
                rm[r] = fmaxf(rm[r], __shfl_xor(rm[r], off));

        float alpha[4];
        #pragma unroll
        for (int r = 0; r < 4; ++r) {
            const float mn = fmaxf(m_run[r], rm[r]);
            alpha[r] = exp2f(m_run[r] - mn);
            m_run[r] = mn;
        }

        float rs[4] = {0.f, 0.f, 0.f, 0.f};
        #pragma unroll
        for (int nt = 0; nt < 4; ++nt)
            #pragma unroll
            for (int r = 0; r < 4; ++r) {
                const float p = exp2f(s[nt][r] - m_run[r]);
                s[nt][r] = p;
                rs[r] += p;
            }
        #pragma unroll
        for (int off = 1; off < 16; off <<= 1)
            #pragma unroll
            for (int r = 0; r < 4; ++r)
                rs[r] += __shfl_xor(rs[r], off);
        #pragma unroll
        for (int r = 0; r < 4; ++r) l_run[r] = l_run[r] * alpha[r] + rs[r];

        #pragma unroll
        for (int r = 0; r < 4; ++r) {
            o[0][r] *= alpha[r]; o[1][r] *= alpha[r];
            o[2][r] *= alpha[r]; o[3][r] *= alpha[r];
        }

        // P: C-layout -> A-layout via per-wave-private strip (stride 72!)
        #pragma unroll
        for (int nt = 0; nt < 4; ++nt)
            #pragma unroll
            for (int r = 0; r < 4; ++r)
                Ps[wave][(quad * 4 + r) * 72 + nt * 16 + l16] = bf16_bits(s[nt][r]);

        const short8 pf0 = *(const short8*)&Ps[wave][l16 * 72 + quad * 8];
        const short8 pf1 = *(const short8*)&Ps[wave][l16 * 72 + 32 + quad * 8];

        __builtin_amdgcn_s_setprio(1);
        #pragma unroll
        for (int nt = 0; nt < 4; ++nt) {
            const short8 vA = *(const short8*)(vtile + ((0 * 4 + nt) * 64 + lane) * 8);
            const short8 vB = *(const short8*)(vtile + ((1 * 4 + nt) * 64 + lane) * 8);
            o[nt] = __builtin_amdgcn_mfma_f32_16x16x32_bf16(pf0, vA, o[nt], 0, 0, 0);
            o[nt] = __builtin_amdgcn_mfma_f32_16x16x32_bf16(pf1, vB, o[nt], 0, 0, 0);
        }
        __builtin_amdgcn_s_setprio(0);

        // one barrier per tile: my ds_reads done (lgkm) + stage landed (vm),
        // then everyone may read buf(kt+1) / overwrite buf(kt) next iter.
        __syncthreads();
    }

    // ---- epilogue: per-wave transpose via LDS (kv region now free) ----
    float inv[4];
    #pragma unroll
    for (int r = 0; r < 4; ++r) inv[r] = 1.0f / l_run[r];
    #pragma unroll
    for (int nt = 0; nt < 4; ++nt)
        #pragma unroll
        for (int r = 0; r < 4; ++r)
            Obuf[wave * 1088 + (quad * 4 + r) * 68 + nt * 16 + l16] = o[nt][r] * inv[r];
    // each wave reads only its own strip -> no cross-wave barrier needed
    {
        const int row = lane >> 2;          // 0..15
        const int c0  = (lane & 3) * 16;    // 0,16,32,48
        float* dst = out + ((size_t)b * Seq + (size_t)qs * 16 + row) * Hd + c0;
        const float* src = &Obuf[wave * 1088 + row * 68 + c0];
        #pragma unroll
        for (int j = 0; j < 4; ++j)
            *(float4*)(dst + j * 4) = *(const float4*)(src + j * 4);
    }
}

// ---------------------------------------------------------------------------
extern "C" void kernel_launch(void* const* d_in, const int* in_sizes, int n_in,
                              void* d_out, int out_size, void* d_ws, size_t ws_size,
                              hipStream_t stream)
{
    const float* x  = (const float*)d_in[0];
    const float* Wq = (const float*)d_in[1];
    const float* bq = (const float*)d_in[2];
    const float* Wk = (const float*)d_in[3];
    const float* bk = (const float*)d_in[4];
    const float* Wv = (const float*)d_in[5];
    const float* bv = (const float*)d_in[6];
    float* out = (float*)d_out;

    short* Qf = (short*)d_ws;                    // 4 MB
    short* Kf = Qf + (size_t)Rows * Hd;          // 4 MB
    short* Vf = Kf + (size_t)Rows * Hd;          // 4 MB
    short* Wf = Vf + (size_t)Rows * Hd;          // 384 KB

    wt_prep<<<96, 256, 0, stream>>>(Wq, Wk, Wv, Wf);
    qkv_kernel<<<512, 256, 0, stream>>>(x, Wf, bq, bk, bv, Qf, Kf, Vf);
    attn_kernel<<<dim3(32, 16), 256, 0, stream>>>(Qf, Kf, Vf, out);
}